// Round 10
// baseline (1665.875 us; speedup 1.0000x reference)
//
#include <hip/hip_runtime.h>
#include <hip/hip_bf16.h>
#include <cmath>

#define NNODES 100000
#define NEDGES 1600000
#define INF 256
#define HH 4
#define DD 32
#define HD 128
#define NEG_SLOPE 0.2f

#define NB 1563            // buckets of 64 dst nodes: 1563*64 = 100032 >= NNODES
#define NBG (NB * 8)       // sub-streams: bucket x (blockIdx&7)   = 12504
#define EBLK 6250          // edge-pass blocks: 6250*256 = 1600000 exactly

typedef __attribute__((ext_vector_type(8))) short short8;   // 8 bf16 = 4 VGPR
typedef __attribute__((ext_vector_type(4))) float f32x4;    // MFMA C/D frag

__device__ __forceinline__ float bf2f(ushort u) {
    union { unsigned int i; float f; } c;
    c.i = ((unsigned int)u) << 16;
    return c.f;
}

// ---------------- fused dual GEMM + el/er (unchanged from round 6)
#define GBM 64
#define GBK 64
__global__ __launch_bounds__(256) void gemm_kernel(const float* __restrict__ feat,
                                                   const float* __restrict__ fc_w,
                                                   const float* __restrict__ res_w,
                                                   const float* __restrict__ attn_l,
                                                   const float* __restrict__ attn_r,
                                                   __hip_bfloat16* __restrict__ ft,
                                                   float* __restrict__ out_rst,
                                                   float* __restrict__ el,
                                                   float* __restrict__ er) {
    __shared__ __align__(16) char Asm[GBM * GBK * 2];    // 8 KB
    __shared__ __align__(16) char Bsm[256 * GBK * 2];    // 32 KB

    const int tid  = threadIdx.x;
    const int lane = tid & 63;
    const int wc   = tid >> 6;
    const int lrow = lane & 15;
    const int lk   = lane >> 4;
    const int m0   = blockIdx.x * GBM;

    f32x4 acc[4][4];
#pragma unroll
    for (int m = 0; m < 4; ++m)
#pragma unroll
        for (int n = 0; n < 4; ++n) acc[m][n] = (f32x4){0.f, 0.f, 0.f, 0.f};

    for (int k0 = 0; k0 < INF; k0 += GBK) {
        if (k0) __syncthreads();
#pragma unroll
        for (int i = 0; i < 2; ++i) {
            int c   = tid + 256 * i;
            int row = c >> 3;
            int cb  = c & 7;
            int off = row * 128 + ((cb * 16) ^ ((row & 7) << 4));
            int grow = m0 + row;
            float4 f0 = make_float4(0.f, 0.f, 0.f, 0.f), f1 = f0;
            if (grow < NNODES) {
                const float* gp = &feat[(size_t)grow * INF + k0 + cb * 8];
                f0 = *(const float4*)gp;
                f1 = *(const float4*)(gp + 4);
            }
            union { short8 v; __hip_bfloat16 h[8]; } pk;
            pk.h[0] = __float2bfloat16(f0.x); pk.h[1] = __float2bfloat16(f0.y);
            pk.h[2] = __float2bfloat16(f0.z); pk.h[3] = __float2bfloat16(f0.w);
            pk.h[4] = __float2bfloat16(f1.x); pk.h[5] = __float2bfloat16(f1.y);
            pk.h[6] = __float2bfloat16(f1.z); pk.h[7] = __float2bfloat16(f1.w);
            *(short8*)(Asm + off) = pk.v;
        }
#pragma unroll
        for (int i = 0; i < 8; ++i) {
            int c   = tid + 256 * i;
            int row = c >> 3;
            int cb  = c & 7;
            int off = row * 128 + ((cb * 16) ^ ((row & 7) << 4));
            const float* wp = (row < 128) ? &fc_w[(size_t)row * 256]
                                          : &res_w[(size_t)(row - 128) * 256];
            float4 f0 = *(const float4*)&wp[k0 + cb * 8];
            float4 f1 = *(const float4*)&wp[k0 + cb * 8 + 4];
            union { short8 v; __hip_bfloat16 h[8]; } pk;
            pk.h[0] = __float2bfloat16(f0.x); pk.h[1] = __float2bfloat16(f0.y);
            pk.h[2] = __float2bfloat16(f0.z); pk.h[3] = __float2bfloat16(f0.w);
            pk.h[4] = __float2bfloat16(f1.x); pk.h[5] = __float2bfloat16(f1.y);
            pk.h[6] = __float2bfloat16(f1.z); pk.h[7] = __float2bfloat16(f1.w);
            *(short8*)(Bsm + off) = pk.v;
        }
        __syncthreads();
#pragma unroll
        for (int ks = 0; ks < 2; ++ks) {
            short8 a[4], b[4];
            int bc = ks * 64 + lk * 16;
#pragma unroll
            for (int m = 0; m < 4; ++m) {
                int row = m * 16 + lrow;
                a[m] = *(const short8*)(Asm + row * 128 + (bc ^ ((row & 7) << 4)));
            }
#pragma unroll
            for (int n = 0; n < 4; ++n) {
                int row = wc * 64 + n * 16 + lrow;
                b[n] = *(const short8*)(Bsm + row * 128 + (bc ^ ((row & 7) << 4)));
            }
#pragma unroll
            for (int m = 0; m < 4; ++m)
#pragma unroll
                for (int n = 0; n < 4; ++n)
                    acc[m][n] = __builtin_amdgcn_mfma_f32_16x16x32_bf16(a[m], b[n], acc[m][n], 0, 0, 0);
        }
    }

    float al[4], ar[4];
    if (wc < 2) {
#pragma unroll
        for (int n = 0; n < 4; ++n) {
            int col = wc * 64 + n * 16 + lrow;
            al[n] = attn_l[col];
            ar[n] = attn_r[col];
        }
    }
#pragma unroll
    for (int m = 0; m < 4; ++m) {
#pragma unroll
        for (int r = 0; r < 4; ++r) {
            int grow = m0 + m * 16 + lk * 4 + r;
            if (grow >= NNODES) continue;
            if (wc < 2) {
                float e_l0, e_l1, e_r0, e_r1;
                {
                    float v0 = acc[m][0][r], v1 = acc[m][1][r];
                    float v2 = acc[m][2][r], v3 = acc[m][3][r];
                    ft[(size_t)grow * HD + wc * 64 + 0 * 16 + lrow] = __float2bfloat16(v0);
                    ft[(size_t)grow * HD + wc * 64 + 1 * 16 + lrow] = __float2bfloat16(v1);
                    ft[(size_t)grow * HD + wc * 64 + 2 * 16 + lrow] = __float2bfloat16(v2);
                    ft[(size_t)grow * HD + wc * 64 + 3 * 16 + lrow] = __float2bfloat16(v3);
                    e_l0 = v0 * al[0] + v1 * al[1];
                    e_l1 = v2 * al[2] + v3 * al[3];
                    e_r0 = v0 * ar[0] + v1 * ar[1];
                    e_r1 = v2 * ar[2] + v3 * ar[3];
                }
#pragma unroll
                for (int msk = 1; msk < 16; msk <<= 1) {
                    e_l0 += __shfl_xor(e_l0, msk);
                    e_l1 += __shfl_xor(e_l1, msk);
                    e_r0 += __shfl_xor(e_r0, msk);
                    e_r1 += __shfl_xor(e_r1, msk);
                }
                if (lrow == 0) {
                    el[grow * HH + wc * 2 + 0] = e_l0;
                    el[grow * HH + wc * 2 + 1] = e_l1;
                    er[grow * HH + wc * 2 + 0] = e_r0;
                    er[grow * HH + wc * 2 + 1] = e_r1;
                }
            } else {
#pragma unroll
                for (int n = 0; n < 4; ++n) {
                    int col = wc * 64 + n * 16 + lrow - 128;
                    out_rst[(size_t)grow * HD + col] = acc[m][n][r];
                }
            }
        }
    }
}

// ---------------- bucket histogram: count[(dst>>6)*8 + (blockIdx&7)]
__global__ void bhist_kernel(const int* __restrict__ dst, int* __restrict__ bcount) {
    int e = blockIdx.x * 256 + threadIdx.x;      // EBLK*256 == NEDGES exactly
    int d = dst[e];
    atomicAdd(&bcount[(d >> 6) * 8 + (blockIdx.x & 7)], 1);
}

// ---------------- exclusive scan of NBG entries in-place; writes total at [NBG]
__global__ __launch_bounds__(1024) void bscan_kernel(int* __restrict__ a) {
    __shared__ int part[1024];
    const int t = threadIdx.x;
    const int CH = (NBG + 1023) / 1024;          // 13
    int v[CH];
    int base = t * CH;
    int s = 0;
#pragma unroll
    for (int i = 0; i < CH; ++i) {
        int idx = base + i;
        v[i] = (idx < NBG) ? a[idx] : 0;
        s += v[i];
    }
    part[t] = s;
    __syncthreads();
    for (int off = 1; off < 1024; off <<= 1) {
        int x = (t >= off) ? part[t - off] : 0;
        __syncthreads();
        part[t] += x;
        __syncthreads();
    }
    int run = part[t] - s;                       // exclusive base for this thread
#pragma unroll
    for (int i = 0; i < CH; ++i) {
        int idx = base + i;
        if (idx < NBG) a[idx] = run;
        run += v[i];
    }
    if (t == 1023) a[NBG] = run;                 // total == NEDGES
}

// ---------------- bucket scatter: (src,dst) into per-(bucket, blockIdx&7) stream
__global__ void bscatter_kernel(const int* __restrict__ src, const int* __restrict__ dst,
                                int* __restrict__ bcursor, int2* __restrict__ bedges) {
    int e = blockIdx.x * 256 + threadIdx.x;
    int s = src[e], d = dst[e];
    int pos = atomicAdd(&bcursor[(d >> 6) * 8 + (blockIdx.x & 7)], 1);
    bedges[pos] = make_int2(s, d);
}

// ---------------- fused softmax + aggregation: one block per 64-dst bucket.
// LDS accumulators; ex recomputed from el/er; 4 edges in flight per wave.
// lane l -> channels 2l,2l+1 (head h = l>>4 for both).
__global__ __launch_bounds__(256) void agg2_kernel(const int* __restrict__ boff,
                                                   const int2* __restrict__ bedges,
                                                   const float* __restrict__ el,
                                                   const float* __restrict__ er,
                                                   const ushort* __restrict__ ft2,
                                                   float* __restrict__ out_rst,
                                                   float* __restrict__ out_agg) {
    __shared__ float acc_s[64 * 128];   // 32 KB
    __shared__ float den_s[64 * 4];
    __shared__ float er_s[64 * 4];
    const int tid   = threadIdx.x;
    const int b     = blockIdx.x;
    const int node0 = b << 6;

    for (int i = tid; i < 64 * 128; i += 256) acc_s[i] = 0.f;
    den_s[tid] = 0.f;
    {
        int n = node0 + (tid >> 2);
        er_s[tid] = (n < NNODES) ? er[n * HH + (tid & 3)] : 0.f;
    }
    __syncthreads();

    const int bstart = boff[b * 8];
    const int bend   = boff[(b + 1) * 8];
    const int wv = tid >> 6, l = tid & 63;
    const int h  = l >> 4;
    const int c0 = l << 1;

    for (int base = bstart + wv * 4; base < bend; base += 16) {
        int last = bend - 1;
        int2 e0 = bedges[base];
        int2 e1 = bedges[min(base + 1, last)];
        int2 e2 = bedges[min(base + 2, last)];
        int2 e3 = bedges[min(base + 3, last)];
        // ex per edge (el gather is L2-resident; er from LDS)
        float x0 = el[e0.x * HH + h] + er_s[(e0.y & 63) * 4 + h];
        float x1 = el[e1.x * HH + h] + er_s[(e1.y & 63) * 4 + h];
        float x2 = el[e2.x * HH + h] + er_s[(e2.y & 63) * 4 + h];
        float x3 = el[e3.x * HH + h] + er_s[(e3.y & 63) * 4 + h];
        x0 = (x0 > 0.f) ? x0 : NEG_SLOPE * x0;
        x1 = (x1 > 0.f) ? x1 : NEG_SLOPE * x1;
        x2 = (x2 > 0.f) ? x2 : NEG_SLOPE * x2;
        x3 = (x3 > 0.f) ? x3 : NEG_SLOPE * x3;
        float ex0 = __expf(x0);
        float ex1 = (base + 1 < bend) ? __expf(x1) : 0.f;
        float ex2 = (base + 2 < bend) ? __expf(x2) : 0.f;
        float ex3 = (base + 3 < bend) ? __expf(x3) : 0.f;
        // 4 independent 256B row gathers
        ushort2 u0 = *(const ushort2*)&ft2[((size_t)e0.x << 7) + c0];
        ushort2 u1 = *(const ushort2*)&ft2[((size_t)e1.x << 7) + c0];
        ushort2 u2 = *(const ushort2*)&ft2[((size_t)e2.x << 7) + c0];
        ushort2 u3 = *(const ushort2*)&ft2[((size_t)e3.x << 7) + c0];
        // LDS accumulate (2 lanes/bank -> conflict-free)
        atomicAdd(&acc_s[(e0.y & 63) * 128 + c0    ], ex0 * bf2f(u0.x));
        atomicAdd(&acc_s[(e0.y & 63) * 128 + c0 + 1], ex0 * bf2f(u0.y));
        atomicAdd(&acc_s[(e1.y & 63) * 128 + c0    ], ex1 * bf2f(u1.x));
        atomicAdd(&acc_s[(e1.y & 63) * 128 + c0 + 1], ex1 * bf2f(u1.y));
        atomicAdd(&acc_s[(e2.y & 63) * 128 + c0    ], ex2 * bf2f(u2.x));
        atomicAdd(&acc_s[(e2.y & 63) * 128 + c0 + 1], ex2 * bf2f(u2.y));
        atomicAdd(&acc_s[(e3.y & 63) * 128 + c0    ], ex3 * bf2f(u3.x));
        atomicAdd(&acc_s[(e3.y & 63) * 128 + c0 + 1], ex3 * bf2f(u3.y));
        if ((l & 15) == 0) {
            atomicAdd(&den_s[(e0.y & 63) * 4 + h], ex0);
            atomicAdd(&den_s[(e1.y & 63) * 4 + h], ex1);
            atomicAdd(&den_s[(e2.y & 63) * 4 + h], ex2);
            atomicAdd(&den_s[(e3.y & 63) * 4 + h], ex3);
        }
    }
    __syncthreads();

    // epilogue: agg = acc/den (den==0 <=> no in-edges), dense writes
    const int c = tid & 127;
    for (int nl = tid >> 7; nl < 64; nl += 2) {
        int n = node0 + nl;
        if (n >= NNODES) break;
        float d = den_s[nl * 4 + (c >> 5)];
        float a = (d > 0.f) ? acc_s[nl * 128 + c] / d : 0.f;
        size_t o = ((size_t)n << 7) + c;
        out_agg[o] = a;
        out_rst[o] += a;     // res staged there by gemm
    }
}

// ---------------- launch
extern "C" void kernel_launch(void* const* d_in, const int* in_sizes, int n_in,
                              void* d_out, int out_size, void* d_ws, size_t ws_size,
                              hipStream_t stream) {
    const float* feat   = (const float*)d_in[0];
    const int*   src    = (const int*)d_in[1];
    const int*   dst    = (const int*)d_in[2];
    const float* fc_w   = (const float*)d_in[3];
    const float* attn_l = (const float*)d_in[4];
    const float* attn_r = (const float*)d_in[5];
    const float* res_w  = (const float*)d_in[6];

    float* out_rst = (float*)d_out;                       // [N][128]
    float* out_agg = out_rst + (size_t)NNODES * HD;       // [N][128]

    char* p = (char*)d_ws;
    auto alloc = [&](size_t bytes) {
        char* r = p;
        p += (bytes + 255) & ~(size_t)255;
        return (void*)r;
    };
    __hip_bfloat16* ft = (__hip_bfloat16*)alloc((size_t)NNODES * HD * 2);  // 25.6 MB
    float* el       = (float*)alloc((size_t)NNODES * HH * 4);              // 1.6 MB
    float* er       = (float*)alloc((size_t)NNODES * HH * 4);              // 1.6 MB
    int*   bcount   = (int*)alloc((size_t)(NBG + 1) * 4);                  // 50 KB (-> boff)
    int*   bcursor  = (int*)alloc((size_t)NBG * 4);                        // 50 KB
    int2*  bedges   = (int2*)alloc((size_t)NEDGES * 8);                    // 12.8 MB

    hipMemsetAsync(bcount, 0, (size_t)(NBG + 1) * 4, stream);

    gemm_kernel<<<(NNODES + GBM - 1) / GBM, 256, 0, stream>>>(
        feat, fc_w, res_w, attn_l, attn_r, ft, out_rst, el, er);
    bhist_kernel<<<EBLK, 256, 0, stream>>>(dst, bcount);
    bscan_kernel<<<1, 1024, 0, stream>>>(bcount);
    hipMemcpyAsync(bcursor, bcount, (size_t)NBG * 4, hipMemcpyDeviceToDevice, stream);
    bscatter_kernel<<<EBLK, 256, 0, stream>>>(src, dst, bcursor, bedges);
    agg2_kernel<<<NB, 256, 0, stream>>>(bcount, bedges, el, er,
                                        (const ushort*)ft, out_rst, out_agg);
}